// Round 8
// baseline (894.300 us; speedup 1.0000x reference)
//
#include <hip/hip_runtime.h>
#include <math.h>

// Problem constants
#define B_    256
#define T_    10
#define D_    512
#define H_    1024
#define FF_   2048
#define NHEAD 16
#define HD    64
#define M_    (B_ * T_)   // 2560 tokens
#define NL    2

typedef unsigned short u16;
typedef unsigned int   u32;
typedef __attribute__((ext_vector_type(8))) short bf16x8;
typedef __attribute__((ext_vector_type(4))) float f32x4;

__device__ inline float sigmoidf_(float x) { return 1.0f / (1.0f + expf(-x)); }
__device__ inline float b2f(u16 v) { return __uint_as_float(((u32)v) << 16); }
__device__ inline u16 f2b(float f) {
    u32 u = __float_as_uint(f);
    return (u16)((u + 0x7fffu + ((u >> 16) & 1u)) >> 16);
}

struct u16x8 { u16 v[8]; };
struct u16x4 { u16 v[4]; };

// ---------------------------------------------------------------------------
// All 8 weight matrices + input x -> one contiguous bf16 arena.
// 8 elems/thread: 2x float4 load, one 16 B store. All split points % 8 == 0.
// ---------------------------------------------------------------------------
__global__ __launch_bounds__(256) void cvt_weights(
    const float* __restrict__ fcw, const float* __restrict__ inp,
    const float* __restrict__ outp, const float* __restrict__ f1,
    const float* __restrict__ f2, const float* __restrict__ wih,
    const float* __restrict__ whh, const float* __restrict__ o1w,
    const float* __restrict__ xin,
    u16* __restrict__ wb)
{
    const int e = (blockIdx.x * 256 + threadIdx.x) * 8;
    const float* src; int off;
    if      (e <   524288) { src = fcw;  off = 0; }
    else if (e <  3670016) { src = inp;  off = 524288; }
    else if (e <  4718592) { src = outp; off = 3670016; }
    else if (e <  6815744) { src = f1;   off = 4718592; }
    else if (e <  8912896) { src = f2;   off = 6815744; }
    else if (e < 13107200) { src = wih;  off = 8912896; }
    else if (e < 17301504) { src = whh;  off = 13107200; }
    else if (e < 17825792) { src = o1w;  off = 17301504; }
    else                   { src = xin;  off = 17825792; }
    const float* p = src + (e - off);
    const float4 x0 = *((const float4*)p);
    const float4 x1 = *((const float4*)(p + 4));
    u16x8 r;
    r.v[0] = f2b(x0.x); r.v[1] = f2b(x0.y); r.v[2] = f2b(x0.z); r.v[3] = f2b(x0.w);
    r.v[4] = f2b(x1.x); r.v[5] = f2b(x1.y); r.v[6] = f2b(x1.z); r.v[7] = f2b(x1.w);
    *((u16x8*)(wb + e)) = r;
}

// ---------------------------------------------------------------------------
// MFMA bf16 GEMM, single-barrier double-buffered pipeline, generic BK.
//   stage(buf0); sync; loop { prefetch buf1; compute buf0; sync; swap }
// Round-6 evidence: BK=64 dbuf (64 KB, 2 blk/CU) > BK=32 dbuf (32 KB,
// 4 blk/CU) — barrier amortization beats occupancy here (r7 regression).
// Fat 128x256/BK=32 keeps 32 MFMA per barrier per wave AND shrinks grids to
// one residency round (r6 wih ran 640 blocks on 512 slots = 38% tail idle).
// 256 threads = 4 waves in 2x2; XCD-aware swizzle.
// ---------------------------------------------------------------------------
template<int BM, int BN, int BK, bool RELU, bool WF32, bool WB16>
__global__ __launch_bounds__(256) void gemm_mfma(const u16* __restrict__ A,
                                                 const u16* __restrict__ W,
                                                 const float* __restrict__ bias,
                                                 float* __restrict__ Cf,
                                                 u16* __restrict__ Cb,
                                                 int M, int N, int K)
{
    constexpr int MI  = BM / 32;
    constexpr int NJ  = BN / 32;
    constexpr int KKN = BK / 32;            // 32-k sub-tiles per buffer
    constexpr int ASZ = KKN * BM * 32;
    constexpr int BSZ = KKN * BN * 32;
    __shared__ alignas(16) u16 As[2 * ASZ];
    __shared__ alignas(16) u16 Bs[2 * BSZ];

    int bx, by;
    {
        const int gx = gridDim.x, gy = gridDim.y;
        const int total = gx * gy;
        const int id = blockIdx.y * gx + blockIdx.x;
        if (((total & 7) == 0) && ((gy & 3) == 0)) {
            const int per = total >> 3;
            const int lid = (id & 7) * per + (id >> 3);  // XCD-contiguous
            const int band = gx << 2;
            const int g = lid / band;
            const int r = lid - g * band;
            by = (g << 2) + (r & 3);
            bx = r >> 2;
        } else { bx = blockIdx.x; by = blockIdx.y; }
    }

    const int wave = threadIdx.x >> 6;
    const int lane = threadIdx.x & 63;
    const int m0 = by * BM;
    const int n0 = bx * BN;
    const int wm = (wave >> 1) * (BM / 2);
    const int wn = (wave & 1) * (BN / 2);
    const int lr = lane >> 2;
    const int lc = (lane & 3) * 8;
    const int fr = lane & 15;
    const int kq = lane >> 4;

    auto stage = [&](int buf, int k0) {
#pragma unroll
        for (int cc = 0; cc < BM / 64; ++cc) {
            const int c = cc * 4 + wave;
            const u16* g = A + (size_t)(m0 + c * 16 + lr) * K + k0 + lc;
#pragma unroll
            for (int kk = 0; kk < KKN; ++kk)
                __builtin_amdgcn_global_load_lds(
                    (const __attribute__((address_space(1))) void*)(g + kk * 32),
                    (__attribute__((address_space(3))) void*)(As + buf * ASZ + kk * BM * 32 + c * 512), 16, 0, 0);
        }
#pragma unroll
        for (int cc = 0; cc < BN / 64; ++cc) {
            const int c = cc * 4 + wave;
            const u16* g = W + (size_t)(n0 + c * 16 + lr) * K + k0 + lc;
#pragma unroll
            for (int kk = 0; kk < KKN; ++kk)
                __builtin_amdgcn_global_load_lds(
                    (const __attribute__((address_space(1))) void*)(g + kk * 32),
                    (__attribute__((address_space(3))) void*)(Bs + buf * BSZ + kk * BN * 32 + c * 512), 16, 0, 0);
        }
    };

    f32x4 acc[MI][NJ] = {};

    stage(0, 0);
    __syncthreads();
    int cur = 0;
    for (int k0 = 0; k0 < K; k0 += BK) {
        if (k0 + BK < K) stage(cur ^ 1, k0 + BK);
#pragma unroll
        for (int kk = 0; kk < KKN; ++kk) {
            bf16x8 a[MI], b[NJ];
#pragma unroll
            for (int i = 0; i < MI; ++i)
                a[i] = *(const bf16x8*)(As + cur * ASZ + kk * BM * 32 + (wm + i * 16 + fr) * 32 + kq * 8);
#pragma unroll
            for (int j = 0; j < NJ; ++j)
                b[j] = *(const bf16x8*)(Bs + cur * BSZ + kk * BN * 32 + (wn + j * 16 + fr) * 32 + kq * 8);
#pragma unroll
            for (int i = 0; i < MI; ++i)
#pragma unroll
                for (int j = 0; j < NJ; ++j)
                    acc[i][j] = __builtin_amdgcn_mfma_f32_16x16x32_bf16(a[i], b[j], acc[i][j], 0, 0, 0);
        }
        __syncthreads();
        cur ^= 1;
    }

#pragma unroll
    for (int i = 0; i < MI; ++i) {
#pragma unroll
        for (int j = 0; j < NJ; ++j) {
            const int col = n0 + wn + j * 16 + fr;
            const float bv = bias ? bias[col] : 0.0f;
#pragma unroll
            for (int r = 0; r < 4; ++r) {
                const int row = m0 + wm + i * 16 + kq * 4 + r;
                float v = acc[i][j][r] + bv;
                if (RELU) v = fmaxf(v, 0.0f);
                if (WF32) Cf[(size_t)row * N + col] = v;
                if (WB16) Cb[(size_t)row * N + col] = f2b(v);
            }
        }
    }
}

// ---------------------------------------------------------------------------
// Fused LSTM timestep (round-6 proven config). Grid (64,4) = 256 blocks.
// Block = 64 b x 16 j (x4 gates = 64 W rows): 64x64 MFMA tile, BK=128
// double-buffered single-barrier K-loop (64 KB LDS), pointwise in-kernel.
// Gate biases (b_ih+b_hh) applied in the pointwise (gx GEMM is bias-free).
// Per-launch barrier between steps (coop grid.sync measured ~40 µs — r4).
// ---------------------------------------------------------------------------
__global__ __launch_bounds__(256) void lstm_step(const u16* __restrict__ h_in,
                                                 const u16* __restrict__ Whh,
                                                 const u16* __restrict__ gx,
                                                 const float* __restrict__ bih,
                                                 const float* __restrict__ bhh,
                                                 float* __restrict__ cstate,
                                                 u16* __restrict__ h_out,
                                                 float* __restrict__ lout_f,
                                                 u16* __restrict__ lout_b,
                                                 int t,
                                                 float* __restrict__ hT_out,
                                                 float* __restrict__ cT_out)
{
    // [buf][As 8192 u16 | Bs 8192 u16] x2 = 64 KB; ghs (64x65 f32) aliases
    __shared__ alignas(16) u16 smem[2 * 16384];
    float* ghs = (float*)smem;

    const int j0 = blockIdx.x * 16;     // 0..1008
    const int b0 = blockIdx.y * 64;     // 0..192

    const int wave = threadIdx.x >> 6;
    const int lane = threadIdx.x & 63;
    const int wm = (wave >> 1) * 32;
    const int wn = (wave & 1) * 32;
    const int lr = lane >> 2;
    const int lc = (lane & 3) * 8;
    const int fr = lane & 15;
    const int kq = lane >> 4;

    auto stage = [&](int buf, int k0) {
        const u16* ga = h_in + (size_t)(b0 + wave * 16 + lr) * H_ + k0 + lc;
#pragma unroll
        for (int kk = 0; kk < 4; ++kk)
            __builtin_amdgcn_global_load_lds(
                (const __attribute__((address_space(1))) void*)(ga + kk * 32),
                (__attribute__((address_space(3))) void*)(smem + buf * 16384 + kk * 2048 + wave * 512), 16, 0, 0);
        const u16* gb = Whh + (size_t)(wave * H_ + j0 + lr) * H_ + k0 + lc;
#pragma unroll
        for (int kk = 0; kk < 4; ++kk)
            __builtin_amdgcn_global_load_lds(
                (const __attribute__((address_space(1))) void*)(gb + kk * 32),
                (__attribute__((address_space(3))) void*)(smem + buf * 16384 + 8192 + kk * 2048 + wave * 512), 16, 0, 0);
    };

    f32x4 acc[2][2] = {};

    stage(0, 0);
    __syncthreads();
    int cur = 0;
    for (int k0 = 0; k0 < H_; k0 += 128) {
        if (k0 + 128 < H_) stage(cur ^ 1, k0 + 128);
        const u16* As = smem + cur * 16384;
        const u16* Bs = As + 8192;
#pragma unroll
        for (int kk = 0; kk < 4; ++kk) {
            bf16x8 a[2], b[2];
#pragma unroll
            for (int i = 0; i < 2; ++i)
                a[i] = *(const bf16x8*)(As + kk * 2048 + (wm + i * 16 + fr) * 32 + kq * 8);
#pragma unroll
            for (int j = 0; j < 2; ++j)
                b[j] = *(const bf16x8*)(Bs + kk * 2048 + (wn + j * 16 + fr) * 32 + kq * 8);
#pragma unroll
            for (int i = 0; i < 2; ++i)
#pragma unroll
                for (int j = 0; j < 2; ++j)
                    acc[i][j] = __builtin_amdgcn_mfma_f32_16x16x32_bf16(a[i], b[j], acc[i][j], 0, 0, 0);
        }
        __syncthreads();
        cur ^= 1;
    }

    // dump ghh tile -> ghs[b-local][rl] (stride 65; smem is dead now)
#pragma unroll
    for (int i = 0; i < 2; ++i)
#pragma unroll
        for (int j = 0; j < 2; ++j) {
            const int rl = wn + j * 16 + fr;
#pragma unroll
            for (int r = 0; r < 4; ++r) {
                const int bl = wm + i * 16 + kq * 4 + r;
                ghs[bl * 65 + rl] = acc[i][j][r];
            }
        }
    __syncthreads();

    // pointwise: thread -> (b_, 4 consecutive j); gates at rl = g*16 + jj
    {
        const int bl = threadIdx.x >> 2;             // 0..63
        const int jq = threadIdx.x & 3;              // 0..3
        const int b_ = b0 + bl;
        const int jbase = jq * 4;                    // jj = jbase+q in 0..15
        const u16* g1 = gx + (size_t)(b_ * T_ + t) * (4 * H_) + j0 + jbase;
        float hh4[4], c4[4];
#pragma unroll
        for (int q = 0; q < 4; ++q) {
            const int jj = jbase + q;
            const int jg = j0 + jbase + q;
            const float gi = b2f(g1[q])          + bih[jg]           + bhh[jg]           + ghs[bl * 65 +  0 + jj];
            const float gf = b2f(g1[H_ + q])     + bih[H_ + jg]      + bhh[H_ + jg]      + ghs[bl * 65 + 16 + jj];
            const float gg = b2f(g1[2 * H_ + q]) + bih[2 * H_ + jg]  + bhh[2 * H_ + jg]  + ghs[bl * 65 + 32 + jj];
            const float go = b2f(g1[3 * H_ + q]) + bih[3 * H_ + jg]  + bhh[3 * H_ + jg]  + ghs[bl * 65 + 48 + jj];
            const int sid = b_ * H_ + jg;
            const float c  = sigmoidf_(gf) * cstate[sid] + sigmoidf_(gi) * tanhf(gg);
            const float hh = sigmoidf_(go) * tanhf(c);
            cstate[sid] = c;
            c4[q] = c;
            hh4[q] = hh;
        }
        u16*   hp = h_out  + (size_t)b_ * H_ + j0 + jbase;
        float* lf = lout_f + (size_t)(b_ * T_ + t) * H_ + j0 + jbase;
        u16*   lb = lout_b + (size_t)(b_ * T_ + t) * H_ + j0 + jbase;
#pragma unroll
        for (int q = 0; q < 4; ++q) {
            const u16 hb16 = f2b(hh4[q]);
            hp[q] = hb16;
            lf[q] = hh4[q];
            lb[q] = hb16;
        }
        if (hT_out) {
#pragma unroll
            for (int q = 0; q < 4; ++q) {
                hT_out[(size_t)b_ * (NL * H_) + j0 + jbase + q] = hh4[q];
                cT_out[(size_t)b_ * (NL * H_) + j0 + jbase + q] = c4[q];
            }
        }
    }
}

// ---------------------------------------------------------------------------
// Causal MHA for one (batch, head), bf16 qkv in, bf16 ctx out.
// ---------------------------------------------------------------------------
__global__ __launch_bounds__(256) void attn_kernel(const u16* __restrict__ qkv,
                                                   u16* __restrict__ ctx)
{
    const int bh = blockIdx.x;
    const int b  = bh >> 4;
    const int h  = bh & 15;

    __shared__ float q[T_][HD], k[T_][HD], v[T_][HD];
    __shared__ float p[T_][T_];

    for (int idx = threadIdx.x; idx < T_ * HD; idx += 256) {
        const int t = idx >> 6, d = idx & 63;
        const u16* row = qkv + (size_t)(b * T_ + t) * (3 * H_) + h * HD + d;
        q[t][d] = b2f(row[0]);
        k[t][d] = b2f(row[H_]);
        v[t][d] = b2f(row[2 * H_]);
    }
    __syncthreads();

    if (threadIdx.x < T_ * T_) {
        const int qi = threadIdx.x / T_, ki = threadIdx.x % T_;
        float s = 0.0f;
        if (ki <= qi) {
            for (int d = 0; d < HD; ++d) s = fmaf(q[qi][d], k[ki][d], s);
            s *= 0.125f;
        }
        p[qi][ki] = s;
    }
    __syncthreads();

    if (threadIdx.x < T_) {
        const int rq = threadIdx.x;
        float mx = -1e30f;
        for (int ki = 0; ki <= rq; ++ki) mx = fmaxf(mx, p[rq][ki]);
        float sum = 0.0f;
        for (int ki = 0; ki <= rq; ++ki) { const float e = expf(p[rq][ki] - mx); p[rq][ki] = e; sum += e; }
        const float inv = 1.0f / sum;
        for (int ki = 0; ki <= rq; ++ki) p[rq][ki] *= inv;
        for (int ki = rq + 1; ki < T_; ++ki) p[rq][ki] = 0.0f;
    }
    __syncthreads();

    for (int idx = threadIdx.x; idx < T_ * HD; idx += 256) {
        const int t = idx >> 6, d = idx & 63;
        float s = 0.0f;
        for (int ki = 0; ki <= t; ++ki) s = fmaf(p[t][ki], v[ki][d], s);
        ctx[(size_t)(b * T_ + t) * H_ + h * HD + d] = f2b(s);
    }
}

// ---------------------------------------------------------------------------
// Fused residual-add + LayerNorm, float4 I/O. Writes f32 and/or bf16.
// ---------------------------------------------------------------------------
__global__ __launch_bounds__(256) void ln_kernel(const float* __restrict__ x,
                                                 const float* __restrict__ res,
                                                 const float* __restrict__ w,
                                                 const float* __restrict__ b,
                                                 float* __restrict__ outf,
                                                 u16* __restrict__ outb)
{
    const int row = blockIdx.x;
    const int c = threadIdx.x * 4;
    const float4 xv = *(const float4*)(x + (size_t)row * H_ + c);
    const float4 rv = *(const float4*)(res + (size_t)row * H_ + c);
    float vals[4] = { xv.x + rv.x, xv.y + rv.y, xv.z + rv.z, xv.w + rv.w };
    float s = 0.0f, s2 = 0.0f;
#pragma unroll
    for (int i = 0; i < 4; ++i) { s += vals[i]; s2 = fmaf(vals[i], vals[i], s2); }
    for (int off = 32; off; off >>= 1) {
        s  += __shfl_down(s, off);
        s2 += __shfl_down(s2, off);
    }
    __shared__ float rs_[4], rs2_[4];
    const int wave = threadIdx.x >> 6, lane = threadIdx.x & 63;
    if (lane == 0) { rs_[wave] = s; rs2_[wave] = s2; }
    __syncthreads();
    const float st  = rs_[0] + rs_[1] + rs_[2] + rs_[3];
    const float st2 = rs2_[0] + rs2_[1] + rs2_[2] + rs2_[3];
    const float m   = st * (1.0f / 1024.0f);
    const float var = st2 * (1.0f / 1024.0f) - m * m;
    const float rsv = rsqrtf(var + 1e-5f);
    const float4 wv = *(const float4*)(w + c);
    const float4 bv = *(const float4*)(b + c);
    float o[4];
    o[0] = (vals[0] - m) * rsv * wv.x + bv.x;
    o[1] = (vals[1] - m) * rsv * wv.y + bv.y;
    o[2] = (vals[2] - m) * rsv * wv.z + bv.z;
    o[3] = (vals[3] - m) * rsv * wv.w + bv.w;
    if (outf) *(float4*)(outf + (size_t)row * H_ + c) = make_float4(o[0], o[1], o[2], o[3]);
    if (outb) {
        u16x4 ob = { { f2b(o[0]), f2b(o[1]), f2b(o[2]), f2b(o[3]) } };
        *(u16x4*)(outb + (size_t)row * H_ + c) = ob;
    }
}

__global__ __launch_bounds__(256) void init_states(const float* __restrict__ uvec,
                                                   const float* __restrict__ gvec,
                                                   int layer,
                                                   u16* __restrict__ hstate_b,
                                                   float* __restrict__ cstate)
{
    const int id = blockIdx.x * 256 + threadIdx.x;
    const int b  = id >> 10;
    const int j  = id & 1023;
    hstate_b[id] = f2b(uvec[(size_t)(b * NL + layer) * H_ + j]);
    cstate[id]   = gvec[(size_t)(b * NL + layer) * H_ + j];
}

// ---------------------------------------------------------------------------
// Head: o = o1 @ out2_w^T + out2_b (N=2) + log_softmax. One wave per token.
// ---------------------------------------------------------------------------
__global__ __launch_bounds__(256) void head_kernel(const float* __restrict__ o1,
                                                   const float* __restrict__ w2,
                                                   const float* __restrict__ b2,
                                                   float* __restrict__ out)
{
    const int token = blockIdx.x * 4 + (threadIdx.x >> 6);
    const int lane  = threadIdx.x & 63;
    const float* row = o1 + (size_t)token * (H_ / 2);
    float s0 = 0.0f, s1 = 0.0f;
    for (int c = lane; c < H_ / 2; c += 64) {
        const float xv = row[c];
        s0 = fmaf(xv, w2[c], s0);
        s1 = fmaf(xv, w2[H_ / 2 + c], s1);
    }
    for (int off = 32; off; off >>= 1) {
        s0 += __shfl_down(s0, off);
        s1 += __shfl_down(s1, off);
    }
    if (lane == 0) {
        const float o0 = s0 + b2[0];
        const float o1v = s1 + b2[1];
        const float mx = fmaxf(o0, o1v);
        const float lse = mx + logf(expf(o0 - mx) + expf(o1v - mx));
        out[(size_t)token * 2 + 0] = o0 - lse;
        out[(size_t)token * 2 + 1] = o1v - lse;
    }
}

// ---------------------------------------------------------------------------
extern "C" void kernel_launch(void* const* d_in, const int* in_sizes, int n_in,
                              void* d_out, int out_size, void* d_ws, size_t ws_size,
                              hipStream_t stream)
{
    const float* x         = (const float*)d_in[0];
    const float* user_vec  = (const float*)d_in[1];
    const float* game_vec  = (const float*)d_in[2];
    const float* fc_w      = (const float*)d_in[3];
    const float* fc_b      = (const float*)d_in[4];
    const float* in_proj_w = (const float*)d_in[5];
    const float* in_proj_b = (const float*)d_in[6];
    const float* out_proj_w= (const float*)d_in[7];
    const float* out_proj_b= (const float*)d_in[8];
    const float* ln1_w     = (const float*)d_in[9];
    const float* ln1_b     = (const float*)d_in[10];
    const float* ff1_w     = (const float*)d_in[11];
    const float* ff1_b     = (const float*)d_in[12];
    const float* ff2_w     = (const float*)d_in[13];
    const float* ff2_b     = (const float*)d_in[14];
    const float* ln2_w     = (const float*)d_in[15];
    const float* ln2_b     = (const float*)d_in[16];
    const float* w_ih      = (const float*)d_in[17];
    const float* w_hh      = (const float*)d_in[18];
    const float* b_ih      = (const float*)d_in[19];
    const float* b_hh      = (const float*)d_in[20];
    const float* out1_w    = (const float*)d_in[21];
    const float* out1_b    = (const float*)d_in[22];
    const float* out2_w    = (const float*)d_in[23];
    const float* out2_b    = (const float*)d_in[24];
    float* out = (float*)d_out;

    // ---- byte arena ----
    char* base = (char*)d_ws;
    u16* wb = (u16*)base;               // bf16 arena: 8 weights + x (contiguous)
    u16* fc_wb   = wb;
    u16* inp_wb  = wb + 524288;
    u16* outp_wb = wb + 3670016;
    u16* ff1_wb  = wb + 4718592;
    u16* ff2_wb  = wb + 6815744;
    u16* wih_b   = wb + 8912896;
    u16* whh_b   = wb + 13107200;
    u16* out1_wb = wb + 17301504;
    u16* x_b     = wb + 17825792;       // [M,D] bf16
    char* A1 = base + 38273024;   // 21.0 MB: qkv_b | tmp1+tmp2 f32 | gx_b | o1
    char* S1 = A1 + 20971520;     // 10.5 MB: ff1_b
    char* S2 = S1 + 10485760;     //  5.2 MB: ctx_b | ln1_b | enc_b
    u16*  hb = (u16*)(S2 + 5242880);              // h bf16 [M,H]
    float* buf0 = (float*)((char*)hb + 5242880);  // h f32 [M,H]
    float* cstate = (float*)((char*)buf0 + 10485760);
    u16*  hs0 = (u16*)((char*)cstate + 1048576);  // LSTM h ping
    u16*  hs1 = (u16*)((char*)hs0 + 524288);      // LSTM h pong

    u16*   qkv_b = (u16*)A1;
    float* tmp1  = (float*)A1;
    float* tmp2  = (float*)(A1 + 10485760);
    u16*   gx_b  = (u16*)A1;
    float* o1    = (float*)A1;
    u16*   ff1b  = (u16*)S1;
    u16*   ctx_b = (u16*)S2;
    u16*   ln1b  = (u16*)S2;
    u16*   enc_b = (u16*)S2;

    float* gv_out = out + (size_t)M_ * 2;            // cT [B,NL,H]
    float* uv_out = gv_out + (size_t)B_ * NL * H_;   // hT [B,NL,H]

    hipLaunchKernelGGL(cvt_weights, dim3(19136512 / 8 / 256), dim3(256), 0, stream,
                       fc_w, in_proj_w, out_proj_w, ff1_w, ff2_w, w_ih, w_hh, out1_w,
                       x, wb);

    // fc: h = relu(x @ fc_w^T + fc_b) -> f32 + bf16
    hipLaunchKernelGGL((gemm_mfma<64, 128, 64, true, true, true>),
                       dim3(H_ / 128, M_ / 64), dim3(256), 0, stream,
                       x_b, fc_wb, fc_b, buf0, hb, M_, H_, D_);

    for (int layer = 0; layer < NL; ++layer) {
        // qkv (bf16 only) — fat 128x256 tile, 240 blocks (one residency round)
        hipLaunchKernelGGL((gemm_mfma<128, 256, 32, false, false, true>),
                           dim3(3 * H_ / 256, M_ / 128), dim3(256), 0, stream,
                           hb, inp_wb, in_proj_b, (float*)nullptr, qkv_b, M_, 3 * H_, H_);
        hipLaunchKernelGGL(attn_kernel, dim3(B_ * NHEAD), dim3(256), 0, stream, qkv_b, ctx_b);
        // attn out-proj (f32 only)
        hipLaunchKernelGGL((gemm_mfma<64, 128, 64, false, true, false>),
                           dim3(H_ / 128, M_ / 64), dim3(256), 0, stream,
                           ctx_b, outp_wb, out_proj_b, tmp1, (u16*)nullptr, M_, H_, H_);
        hipLaunchKernelGGL(ln_kernel, dim3(M_), dim3(256), 0, stream,
                           buf0, tmp1, ln1_w, ln1_b, tmp2, ln1b);
        // ff1 relu (bf16 only) — fat tile, 160 blocks
        hipLaunchKernelGGL((gemm_mfma<128, 256, 32, true, false, true>),
                           dim3(FF_ / 256, M_ / 128), dim3(256), 0, stream,
                           ln1b, ff1_wb, ff1_b, (float*)nullptr, ff1b, M_, FF_, H_);
        // ff2 (f32 only)
        hipLaunchKernelGGL((gemm_mfma<64, 128, 64, false, true, false>),
                           dim3(H_ / 128, M_ / 64), dim3(256), 0, stream,
                           ff1b, ff2_wb, ff2_b, tmp1, (u16*)nullptr, M_, H_, FF_);
        hipLaunchKernelGGL(ln_kernel, dim3(M_), dim3(256), 0, stream,
                           tmp2, tmp1, ln2_w, ln2_b, (float*)nullptr, enc_b);
        // LSTM input gates (bf16 only) — fat tile, 320 blocks (was 640!)
        hipLaunchKernelGGL((gemm_mfma<128, 256, 32, false, false, true>),
                           dim3(4 * H_ / 256, M_ / 128), dim3(256), 0, stream,
                           enc_b, wih_b, (const float*)nullptr, (float*)nullptr, gx_b, M_, 4 * H_, H_);
        hipLaunchKernelGGL(init_states, dim3(B_ * H_ / 256), dim3(256), 0, stream,
                           user_vec, game_vec, layer, hs0, cstate);
        for (int t = 0; t < T_; ++t) {
            const bool last = (t == T_ - 1);
            hipLaunchKernelGGL(lstm_step, dim3(64, 4), dim3(256), 0, stream,
                               (t & 1) ? hs1 : hs0, whh_b, gx_b, b_ih, b_hh, cstate,
                               (t & 1) ? hs0 : hs1, buf0, hb, t,
                               last ? (uv_out + layer * H_) : nullptr,
                               last ? (gv_out + layer * H_) : nullptr);
        }
    }

    // head: o1 = relu(lstm_out @ out1_w^T + out1_b), then 2-class log_softmax
    hipLaunchKernelGGL((gemm_mfma<64, 64, 64, true, true, false>),
                       dim3((H_ / 2) / 64, M_ / 64), dim3(256), 0, stream,
                       hb, out1_wb, out1_b, o1, (u16*)nullptr, M_, H_ / 2, H_);
    hipLaunchKernelGGL(head_kernel, dim3(M_ / 4), dim3(256), 0, stream, o1, out2_w, out2_b, out);
}

// Round 9
// 729.221 us; speedup vs baseline: 1.2264x; 1.2264x over previous
//
#include <hip/hip_runtime.h>
#include <math.h>

// Problem constants
#define B_    256
#define T_    10
#define D_    512
#define H_    1024
#define FF_   2048
#define NHEAD 16
#define HD    64
#define M_    (B_ * T_)   // 2560 tokens
#define NL    2

typedef unsigned short u16;
typedef unsigned int   u32;
typedef __attribute__((ext_vector_type(8))) short bf16x8;
typedef __attribute__((ext_vector_type(4))) float f32x4;

__device__ inline float sigmoidf_(float x) { return 1.0f / (1.0f + expf(-x)); }
__device__ inline float b2f(u16 v) { return __uint_as_float(((u32)v) << 16); }
__device__ inline u16 f2b(float f) {
    u32 u = __float_as_uint(f);
    return (u16)((u + 0x7fffu + ((u >> 16) & 1u)) >> 16);
}

struct u16x8 { u16 v[8]; };
struct u16x4 { u16 v[4]; };

// ---------------------------------------------------------------------------
// All 8 weight matrices + input x -> one contiguous bf16 arena.
// 8 elems/thread: 2x float4 load, one 16 B store. All split points % 8 == 0.
// ---------------------------------------------------------------------------
__global__ __launch_bounds__(256) void cvt_weights(
    const float* __restrict__ fcw, const float* __restrict__ inp,
    const float* __restrict__ outp, const float* __restrict__ f1,
    const float* __restrict__ f2, const float* __restrict__ wih,
    const float* __restrict__ whh, const float* __restrict__ o1w,
    const float* __restrict__ xin,
    u16* __restrict__ wb)
{
    const int e = (blockIdx.x * 256 + threadIdx.x) * 8;
    const float* src; int off;
    if      (e <   524288) { src = fcw;  off = 0; }
    else if (e <  3670016) { src = inp;  off = 524288; }
    else if (e <  4718592) { src = outp; off = 3670016; }
    else if (e <  6815744) { src = f1;   off = 4718592; }
    else if (e <  8912896) { src = f2;   off = 6815744; }
    else if (e < 13107200) { src = wih;  off = 8912896; }
    else if (e < 17301504) { src = whh;  off = 13107200; }
    else if (e < 17825792) { src = o1w;  off = 17301504; }
    else                   { src = xin;  off = 17825792; }
    const float* p = src + (e - off);
    const float4 x0 = *((const float4*)p);
    const float4 x1 = *((const float4*)(p + 4));
    u16x8 r;
    r.v[0] = f2b(x0.x); r.v[1] = f2b(x0.y); r.v[2] = f2b(x0.z); r.v[3] = f2b(x0.w);
    r.v[4] = f2b(x1.x); r.v[5] = f2b(x1.y); r.v[6] = f2b(x1.z); r.v[7] = f2b(x1.w);
    *((u16x8*)(wb + e)) = r;
}

// ---------------------------------------------------------------------------
// MFMA bf16 GEMM — round-6 proven config: BK=64 single-barrier double-buffer
// (64 KB LDS for 128x128, 2 blocks/CU). r7 (BK=32, 4 blk/CU) and r8
// (128x256, 264 unified regs -> 1 wave/SIMD cliff) both regressed; this is
// the bracketed local optimum. NEW in r9: bf16 epilogue repacks through the
// dead staging LDS -> coalesced u16x8 stores (was 64 scalar 2B stores/thd).
// 256 threads = 4 waves in 2x2; XCD-aware swizzle.
// ---------------------------------------------------------------------------
template<int BM, int BN, bool RELU, bool WF32, bool WB16>
__global__ __launch_bounds__(256) void gemm_mfma(const u16* __restrict__ A,
                                                 const u16* __restrict__ W,
                                                 const float* __restrict__ bias,
                                                 float* __restrict__ Cf,
                                                 u16* __restrict__ Cb,
                                                 int M, int N, int K)
{
    constexpr int MI  = BM / 32;
    constexpr int NJ  = BN / 32;
    constexpr int ASZ = 2 * BM * 32;   // u16 per A buffer (2 kk sub-tiles)
    constexpr int BSZ = 2 * BN * 32;
    constexpr int RPS = BN + 8;        // padded repack row stride (u16)
    // single arena so the repack view can span As+Bs
    __shared__ alignas(16) u16 smem[2 * ASZ + 2 * BSZ];
    u16* As = smem;
    u16* Bs = smem + 2 * ASZ;
    static_assert(BM * RPS <= 2 * ASZ + 2 * BSZ, "repack fits");

    int bx, by;
    {
        const int gx = gridDim.x, gy = gridDim.y;
        const int total = gx * gy;
        const int id = blockIdx.y * gx + blockIdx.x;
        if (((total & 7) == 0) && ((gy & 3) == 0)) {
            const int per = total >> 3;
            const int lid = (id & 7) * per + (id >> 3);  // XCD-contiguous
            const int band = gx << 2;
            const int g = lid / band;
            const int r = lid - g * band;
            by = (g << 2) + (r & 3);
            bx = r >> 2;
        } else { bx = blockIdx.x; by = blockIdx.y; }
    }

    const int wave = threadIdx.x >> 6;
    const int lane = threadIdx.x & 63;
    const int m0 = by * BM;
    const int n0 = bx * BN;
    const int wm = (wave >> 1) * (BM / 2);
    const int wn = (wave & 1) * (BN / 2);
    const int lr = lane >> 2;
    const int lc = (lane & 3) * 8;
    const int fr = lane & 15;
    const int kq = lane >> 4;

    auto stage = [&](int buf, int k0) {
#pragma unroll
        for (int cc = 0; cc < BM / 64; ++cc) {
            const int c = cc * 4 + wave;
            const u16* g = A + (size_t)(m0 + c * 16 + lr) * K + k0 + lc;
#pragma unroll
            for (int kk = 0; kk < 2; ++kk)
                __builtin_amdgcn_global_load_lds(
                    (const __attribute__((address_space(1))) void*)(g + kk * 32),
                    (__attribute__((address_space(3))) void*)(As + buf * ASZ + kk * BM * 32 + c * 512), 16, 0, 0);
        }
#pragma unroll
        for (int cc = 0; cc < BN / 64; ++cc) {
            const int c = cc * 4 + wave;
            const u16* g = W + (size_t)(n0 + c * 16 + lr) * K + k0 + lc;
#pragma unroll
            for (int kk = 0; kk < 2; ++kk)
                __builtin_amdgcn_global_load_lds(
                    (const __attribute__((address_space(1))) void*)(g + kk * 32),
                    (__attribute__((address_space(3))) void*)(Bs + buf * BSZ + kk * BN * 32 + c * 512), 16, 0, 0);
        }
    };

    f32x4 acc[MI][NJ] = {};

    stage(0, 0);
    __syncthreads();
    int cur = 0;
    for (int k0 = 0; k0 < K; k0 += 64) {
        if (k0 + 64 < K) stage(cur ^ 1, k0 + 64);
#pragma unroll
        for (int kk = 0; kk < 2; ++kk) {
            bf16x8 a[MI], b[NJ];
#pragma unroll
            for (int i = 0; i < MI; ++i)
                a[i] = *(const bf16x8*)(As + cur * ASZ + kk * BM * 32 + (wm + i * 16 + fr) * 32 + kq * 8);
#pragma unroll
            for (int j = 0; j < NJ; ++j)
                b[j] = *(const bf16x8*)(Bs + cur * BSZ + kk * BN * 32 + (wn + j * 16 + fr) * 32 + kq * 8);
#pragma unroll
            for (int i = 0; i < MI; ++i)
#pragma unroll
                for (int j = 0; j < NJ; ++j)
                    acc[i][j] = __builtin_amdgcn_mfma_f32_16x16x32_bf16(a[i], b[j], acc[i][j], 0, 0, 0);
        }
        __syncthreads();
        cur ^= 1;
    }

    // ---- epilogue ----
    u16* rp = smem;   // staging LDS is dead; repack view [BM][RPS]
#pragma unroll
    for (int i = 0; i < MI; ++i) {
#pragma unroll
        for (int j = 0; j < NJ; ++j) {
            const int cl = wn + j * 16 + fr;
            const float bv = bias ? bias[n0 + cl] : 0.0f;
#pragma unroll
            for (int r = 0; r < 4; ++r) {
                const int rl = wm + i * 16 + kq * 4 + r;
                float v = acc[i][j][r] + bv;
                if (RELU) v = fmaxf(v, 0.0f);
                if (WF32) Cf[(size_t)(m0 + rl) * N + n0 + cl] = v;
                if (WB16) rp[rl * RPS + cl] = f2b(v);
            }
        }
    }
    if (WB16) {
        __syncthreads();
        constexpr int CPR = BN / 8;               // 16B chunks per row
#pragma unroll
        for (int s = 0; s < BM * BN / 2048; ++s) {
            const int e   = s * 256 + threadIdx.x;
            const int row = e / CPR;
            const int ch  = e - row * CPR;
            *(u16x8*)(Cb + (size_t)(m0 + row) * N + n0 + ch * 8) =
                *(const u16x8*)(rp + row * RPS + ch * 8);
        }
    }
}

// ---------------------------------------------------------------------------
// Fused LSTM timestep (round-6 proven config). Grid (64,4) = 256 blocks.
// Block = 64 b x 16 j (x4 gates = 64 W rows): 64x64 MFMA tile, BK=128
// double-buffered single-barrier K-loop (64 KB LDS), pointwise in-kernel.
// Gate biases (b_ih+b_hh) applied in the pointwise (gx GEMM is bias-free).
// Per-launch barrier between steps (coop grid.sync measured ~40 µs — r4).
// lout_f is nullable: the last layer's f32 sequence is never consumed.
// ---------------------------------------------------------------------------
__global__ __launch_bounds__(256) void lstm_step(const u16* __restrict__ h_in,
                                                 const u16* __restrict__ Whh,
                                                 const u16* __restrict__ gx,
                                                 const float* __restrict__ bih,
                                                 const float* __restrict__ bhh,
                                                 float* __restrict__ cstate,
                                                 u16* __restrict__ h_out,
                                                 float* __restrict__ lout_f,
                                                 u16* __restrict__ lout_b,
                                                 int t,
                                                 float* __restrict__ hT_out,
                                                 float* __restrict__ cT_out)
{
    // [buf][As 8192 u16 | Bs 8192 u16] x2 = 64 KB; ghs (64x65 f32) aliases
    __shared__ alignas(16) u16 smem[2 * 16384];
    float* ghs = (float*)smem;

    const int j0 = blockIdx.x * 16;     // 0..1008
    const int b0 = blockIdx.y * 64;     // 0..192

    const int wave = threadIdx.x >> 6;
    const int lane = threadIdx.x & 63;
    const int wm = (wave >> 1) * 32;
    const int wn = (wave & 1) * 32;
    const int lr = lane >> 2;
    const int lc = (lane & 3) * 8;
    const int fr = lane & 15;
    const int kq = lane >> 4;

    auto stage = [&](int buf, int k0) {
        const u16* ga = h_in + (size_t)(b0 + wave * 16 + lr) * H_ + k0 + lc;
#pragma unroll
        for (int kk = 0; kk < 4; ++kk)
            __builtin_amdgcn_global_load_lds(
                (const __attribute__((address_space(1))) void*)(ga + kk * 32),
                (__attribute__((address_space(3))) void*)(smem + buf * 16384 + kk * 2048 + wave * 512), 16, 0, 0);
        const u16* gb = Whh + (size_t)(wave * H_ + j0 + lr) * H_ + k0 + lc;
#pragma unroll
        for (int kk = 0; kk < 4; ++kk)
            __builtin_amdgcn_global_load_lds(
                (const __attribute__((address_space(1))) void*)(gb + kk * 32),
                (__attribute__((address_space(3))) void*)(smem + buf * 16384 + 8192 + kk * 2048 + wave * 512), 16, 0, 0);
    };

    f32x4 acc[2][2] = {};

    stage(0, 0);
    __syncthreads();
    int cur = 0;
    for (int k0 = 0; k0 < H_; k0 += 128) {
        if (k0 + 128 < H_) stage(cur ^ 1, k0 + 128);
        const u16* As = smem + cur * 16384;
        const u16* Bs = As + 8192;
#pragma unroll
        for (int kk = 0; kk < 4; ++kk) {
            bf16x8 a[2], b[2];
#pragma unroll
            for (int i = 0; i < 2; ++i)
                a[i] = *(const bf16x8*)(As + kk * 2048 + (wm + i * 16 + fr) * 32 + kq * 8);
#pragma unroll
            for (int j = 0; j < 2; ++j)
                b[j] = *(const bf16x8*)(Bs + kk * 2048 + (wn + j * 16 + fr) * 32 + kq * 8);
#pragma unroll
            for (int i = 0; i < 2; ++i)
#pragma unroll
                for (int j = 0; j < 2; ++j)
                    acc[i][j] = __builtin_amdgcn_mfma_f32_16x16x32_bf16(a[i], b[j], acc[i][j], 0, 0, 0);
        }
        __syncthreads();
        cur ^= 1;
    }

    // dump ghh tile -> ghs[b-local][rl] (stride 65; smem is dead now)
#pragma unroll
    for (int i = 0; i < 2; ++i)
#pragma unroll
        for (int j = 0; j < 2; ++j) {
            const int rl = wn + j * 16 + fr;
#pragma unroll
            for (int r = 0; r < 4; ++r) {
                const int bl = wm + i * 16 + kq * 4 + r;
                ghs[bl * 65 + rl] = acc[i][j][r];
            }
        }
    __syncthreads();

    // pointwise: thread -> (b_, 4 consecutive j); gates at rl = g*16 + jj
    {
        const int bl = threadIdx.x >> 2;             // 0..63
        const int jq = threadIdx.x & 3;              // 0..3
        const int b_ = b0 + bl;
        const int jbase = jq * 4;                    // jj = jbase+q in 0..15
        const u16* g1 = gx + (size_t)(b_ * T_ + t) * (4 * H_) + j0 + jbase;
        float hh4[4], c4[4];
#pragma unroll
        for (int q = 0; q < 4; ++q) {
            const int jj = jbase + q;
            const int jg = j0 + jbase + q;
            const float gi = b2f(g1[q])          + bih[jg]           + bhh[jg]           + ghs[bl * 65 +  0 + jj];
            const float gf = b2f(g1[H_ + q])     + bih[H_ + jg]      + bhh[H_ + jg]      + ghs[bl * 65 + 16 + jj];
            const float gg = b2f(g1[2 * H_ + q]) + bih[2 * H_ + jg]  + bhh[2 * H_ + jg]  + ghs[bl * 65 + 32 + jj];
            const float go = b2f(g1[3 * H_ + q]) + bih[3 * H_ + jg]  + bhh[3 * H_ + jg]  + ghs[bl * 65 + 48 + jj];
            const int sid = b_ * H_ + jg;
            const float c  = sigmoidf_(gf) * cstate[sid] + sigmoidf_(gi) * tanhf(gg);
            const float hh = sigmoidf_(go) * tanhf(c);
            cstate[sid] = c;
            c4[q] = c;
            hh4[q] = hh;
        }
        u16*   hp = h_out  + (size_t)b_ * H_ + j0 + jbase;
        u16*   lb = lout_b + (size_t)(b_ * T_ + t) * H_ + j0 + jbase;
#pragma unroll
        for (int q = 0; q < 4; ++q) {
            const u16 hb16 = f2b(hh4[q]);
            hp[q] = hb16;
            lb[q] = hb16;
        }
        if (lout_f) {
            float* lf = lout_f + (size_t)(b_ * T_ + t) * H_ + j0 + jbase;
#pragma unroll
            for (int q = 0; q < 4; ++q) lf[q] = hh4[q];
        }
        if (hT_out) {
#pragma unroll
            for (int q = 0; q < 4; ++q) {
                hT_out[(size_t)b_ * (NL * H_) + j0 + jbase + q] = hh4[q];
                cT_out[(size_t)b_ * (NL * H_) + j0 + jbase + q] = c4[q];
            }
        }
    }
}

// ---------------------------------------------------------------------------
// Causal MHA for one (batch, head), bf16 qkv in, bf16 ctx out.
// ---------------------------------------------------------------------------
__global__ __launch_bounds__(256) void attn_kernel(const u16* __restrict__ qkv,
                                                   u16* __restrict__ ctx)
{
    const int bh = blockIdx.x;
    const int b  = bh >> 4;
    const int h  = bh & 15;

    __shared__ float q[T_][HD], k[T_][HD], v[T_][HD];
    __shared__ float p[T_][T_];

    for (int idx = threadIdx.x; idx < T_ * HD; idx += 256) {
        const int t = idx >> 6, d = idx & 63;
        const u16* row = qkv + (size_t)(b * T_ + t) * (3 * H_) + h * HD + d;
        q[t][d] = b2f(row[0]);
        k[t][d] = b2f(row[H_]);
        v[t][d] = b2f(row[2 * H_]);
    }
    __syncthreads();

    if (threadIdx.x < T_ * T_) {
        const int qi = threadIdx.x / T_, ki = threadIdx.x % T_;
        float s = 0.0f;
        if (ki <= qi) {
            for (int d = 0; d < HD; ++d) s = fmaf(q[qi][d], k[ki][d], s);
            s *= 0.125f;
        }
        p[qi][ki] = s;
    }
    __syncthreads();

    if (threadIdx.x < T_) {
        const int rq = threadIdx.x;
        float mx = -1e30f;
        for (int ki = 0; ki <= rq; ++ki) mx = fmaxf(mx, p[rq][ki]);
        float sum = 0.0f;
        for (int ki = 0; ki <= rq; ++ki) { const float e = expf(p[rq][ki] - mx); p[rq][ki] = e; sum += e; }
        const float inv = 1.0f / sum;
        for (int ki = 0; ki <= rq; ++ki) p[rq][ki] *= inv;
        for (int ki = rq + 1; ki < T_; ++ki) p[rq][ki] = 0.0f;
    }
    __syncthreads();

    for (int idx = threadIdx.x; idx < T_ * HD; idx += 256) {
        const int t = idx >> 6, d = idx & 63;
        float s = 0.0f;
        for (int ki = 0; ki <= t; ++ki) s = fmaf(p[t][ki], v[ki][d], s);
        ctx[(size_t)(b * T_ + t) * H_ + h * HD + d] = f2b(s);
    }
}

// ---------------------------------------------------------------------------
// Fused residual-add + LayerNorm, float4 I/O. Writes f32 and/or bf16.
// ---------------------------------------------------------------------------
__global__ __launch_bounds__(256) void ln_kernel(const float* __restrict__ x,
                                                 const float* __restrict__ res,
                                                 const float* __restrict__ w,
                                                 const float* __restrict__ b,
                                                 float* __restrict__ outf,
                                                 u16* __restrict__ outb)
{
    const int row = blockIdx.x;
    const int c = threadIdx.x * 4;
    const float4 xv = *(const float4*)(x + (size_t)row * H_ + c);
    const float4 rv = *(const float4*)(res + (size_t)row * H_ + c);
    float vals[4] = { xv.x + rv.x, xv.y + rv.y, xv.z + rv.z, xv.w + rv.w };
    float s = 0.0f, s2 = 0.0f;
#pragma unroll
    for (int i = 0; i < 4; ++i) { s += vals[i]; s2 = fmaf(vals[i], vals[i], s2); }
    for (int off = 32; off; off >>= 1) {
        s  += __shfl_down(s, off);
        s2 += __shfl_down(s2, off);
    }
    __shared__ float rs_[4], rs2_[4];
    const int wave = threadIdx.x >> 6, lane = threadIdx.x & 63;
    if (lane == 0) { rs_[wave] = s; rs2_[wave] = s2; }
    __syncthreads();
    const float st  = rs_[0] + rs_[1] + rs_[2] + rs_[3];
    const float st2 = rs2_[0] + rs2_[1] + rs2_[2] + rs2_[3];
    const float m   = st * (1.0f / 1024.0f);
    const float var = st2 * (1.0f / 1024.0f) - m * m;
    const float rsv = rsqrtf(var + 1e-5f);
    const float4 wv = *(const float4*)(w + c);
    const float4 bv = *(const float4*)(b + c);
    float o[4];
    o[0] = (vals[0] - m) * rsv * wv.x + bv.x;
    o[1] = (vals[1] - m) * rsv * wv.y + bv.y;
    o[2] = (vals[2] - m) * rsv * wv.z + bv.z;
    o[3] = (vals[3] - m) * rsv * wv.w + bv.w;
    if (outf) *(float4*)(outf + (size_t)row * H_ + c) = make_float4(o[0], o[1], o[2], o[3]);
    if (outb) {
        u16x4 ob = { { f2b(o[0]), f2b(o[1]), f2b(o[2]), f2b(o[3]) } };
        *(u16x4*)(outb + (size_t)row * H_ + c) = ob;
    }
}

__global__ __launch_bounds__(256) void init_states(const float* __restrict__ uvec,
                                                   const float* __restrict__ gvec,
                                                   int layer,
                                                   u16* __restrict__ hstate_b,
                                                   float* __restrict__ cstate)
{
    const int id = blockIdx.x * 256 + threadIdx.x;
    const int b  = id >> 10;
    const int j  = id & 1023;
    hstate_b[id] = f2b(uvec[(size_t)(b * NL + layer) * H_ + j]);
    cstate[id]   = gvec[(size_t)(b * NL + layer) * H_ + j];
}

// ---------------------------------------------------------------------------
// Head: o = o1 @ out2_w^T + out2_b (N=2) + log_softmax. One wave per token.
// ---------------------------------------------------------------------------
__global__ __launch_bounds__(256) void head_kernel(const float* __restrict__ o1,
                                                   const float* __restrict__ w2,
                                                   const float* __restrict__ b2,
                                                   float* __restrict__ out)
{
    const int token = blockIdx.x * 4 + (threadIdx.x >> 6);
    const int lane  = threadIdx.x & 63;
    const float* row = o1 + (size_t)token * (H_ / 2);
    float s0 = 0.0f, s1 = 0.0f;
    for (int c = lane; c < H_ / 2; c += 64) {
        const float xv = row[c];
        s0 = fmaf(xv, w2[c], s0);
        s1 = fmaf(xv, w2[H_ / 2 + c], s1);
    }
    for (int off = 32; off; off >>= 1) {
        s0 += __shfl_down(s0, off);
        s1 += __shfl_down(s1, off);
    }
    if (lane == 0) {
        const float o0 = s0 + b2[0];
        const float o1v = s1 + b2[1];
        const float mx = fmaxf(o0, o1v);
        const float lse = mx + logf(expf(o0 - mx) + expf(o1v - mx));
        out[(size_t)token * 2 + 0] = o0 - lse;
        out[(size_t)token * 2 + 1] = o1v - lse;
    }
}

// ---------------------------------------------------------------------------
extern "C" void kernel_launch(void* const* d_in, const int* in_sizes, int n_in,
                              void* d_out, int out_size, void* d_ws, size_t ws_size,
                              hipStream_t stream)
{
    const float* x         = (const float*)d_in[0];
    const float* user_vec  = (const float*)d_in[1];
    const float* game_vec  = (const float*)d_in[2];
    const float* fc_w      = (const float*)d_in[3];
    const float* fc_b      = (const float*)d_in[4];
    const float* in_proj_w = (const float*)d_in[5];
    const float* in_proj_b = (const float*)d_in[6];
    const float* out_proj_w= (const float*)d_in[7];
    const float* out_proj_b= (const float*)d_in[8];
    const float* ln1_w     = (const float*)d_in[9];
    const float* ln1_b     = (const float*)d_in[10];
    const float* ff1_w     = (const float*)d_in[11];
    const float* ff1_b     = (const float*)d_in[12];
    const float* ff2_w     = (const float*)d_in[13];
    const float* ff2_b     = (const float*)d_in[14];
    const float* ln2_w     = (const float*)d_in[15];
    const float* ln2_b     = (const float*)d_in[16];
    const float* w_ih      = (const float*)d_in[17];
    const float* w_hh      = (const float*)d_in[18];
    const float* b_ih      = (const float*)d_in[19];
    const float* b_hh      = (const float*)d_in[20];
    const float* out1_w    = (const float*)d_in[21];
    const float* out1_b    = (const float*)d_in[22];
    const float* out2_w    = (const float*)d_in[23];
    const float* out2_b    = (const float*)d_in[24];
    float* out = (float*)d_out;

    // ---- byte arena ----
    char* base = (char*)d_ws;
    u16* wb = (u16*)base;               // bf16 arena: 8 weights + x (contiguous)
    u16* fc_wb   = wb;
    u16* inp_wb  = wb + 524288;
    u16* outp_wb = wb + 3670016;
    u16* ff1_wb  = wb + 4718592;
    u16* ff2_wb  = wb + 6815744;
    u16* wih_b   = wb + 8912896;
    u16* whh_b   = wb + 13107200;
    u16* out1_wb = wb + 17301504;
    u16* x_b     = wb + 17825792;       // [M,D] bf16
    char* A1 = base + 38273024;   // 21.0 MB: qkv_b | tmp1+tmp2 f32 | gx_b | o1
    char* S1 = A1 + 20971520;     // 10.5 MB: ff1_b
    char* S2 = S1 + 10485760;     //  5.2 MB: ctx_b | ln1_b | enc_b
    u16*  hb = (u16*)(S2 + 5242880);              // h bf16 [M,H]
    float* buf0 = (float*)((char*)hb + 5242880);  // h f32 [M,H]
    float* cstate = (float*)((char*)buf0 + 10485760);
    u16*  hs0 = (u16*)((char*)cstate + 1048576);  // LSTM h ping
    u16*  hs1 = (u16*)((char*)hs0 + 524288);      // LSTM h pong

    u16*   qkv_b = (u16*)A1;
    float* tmp1  = (float*)A1;
    float* tmp2  = (float*)(A1 + 10485760);
    u16*   gx_b  = (u16*)A1;
    float* o1    = (float*)A1;
    u16*   ff1b  = (u16*)S1;
    u16*   ctx_b = (u16*)S2;
    u16*   ln1b  = (u16*)S2;
    u16*   enc_b = (u16*)S2;

    float* gv_out = out + (size_t)M_ * 2;            // cT [B,NL,H]
    float* uv_out = gv_out + (size_t)B_ * NL * H_;   // hT [B,NL,H]

    hipLaunchKernelGGL(cvt_weights, dim3(19136512 / 8 / 256), dim3(256), 0, stream,
                       fc_w, in_proj_w, out_proj_w, ff1_w, ff2_w, w_ih, w_hh, out1_w,
                       x, wb);

    // fc: h = relu(x @ fc_w^T + fc_b) -> f32 + bf16
    hipLaunchKernelGGL((gemm_mfma<64, 128, true, true, true>),
                       dim3(H_ / 128, M_ / 64), dim3(256), 0, stream,
                       x_b, fc_wb, fc_b, buf0, hb, M_, H_, D_);

    for (int layer = 0; layer < NL; ++layer) {
        const bool last_layer = (layer == NL - 1);
        // qkv (bf16 only)
        hipLaunchKernelGGL((gemm_mfma<128, 128, false, false, true>),
                           dim3(3 * H_ / 128, M_ / 128), dim3(256), 0, stream,
                           hb, inp_wb, in_proj_b, (float*)nullptr, qkv_b, M_, 3 * H_, H_);
        hipLaunchKernelGGL(attn_kernel, dim3(B_ * NHEAD), dim3(256), 0, stream, qkv_b, ctx_b);
        // attn out-proj (f32 only)
        hipLaunchKernelGGL((gemm_mfma<64, 128, false, true, false>),
                           dim3(H_ / 128, M_ / 64), dim3(256), 0, stream,
                           ctx_b, outp_wb, out_proj_b, tmp1, (u16*)nullptr, M_, H_, H_);
        hipLaunchKernelGGL(ln_kernel, dim3(M_), dim3(256), 0, stream,
                           buf0, tmp1, ln1_w, ln1_b, tmp2, ln1b);
        // ff1 relu (bf16 only)
        hipLaunchKernelGGL((gemm_mfma<128, 128, true, false, true>),
                           dim3(FF_ / 128, M_ / 128), dim3(256), 0, stream,
                           ln1b, ff1_wb, ff1_b, (float*)nullptr, ff1b, M_, FF_, H_);
        // ff2 (f32 only)
        hipLaunchKernelGGL((gemm_mfma<64, 128, false, true, false>),
                           dim3(H_ / 128, M_ / 64), dim3(256), 0, stream,
                           ff1b, ff2_wb, ff2_b, tmp1, (u16*)nullptr, M_, H_, FF_);
        hipLaunchKernelGGL(ln_kernel, dim3(M_), dim3(256), 0, stream,
                           tmp2, tmp1, ln2_w, ln2_b, (float*)nullptr, enc_b);
        // LSTM input gates for all t (bf16 only; biases applied in lstm_step)
        hipLaunchKernelGGL((gemm_mfma<128, 128, false, false, true>),
                           dim3(4 * H_ / 128, M_ / 128), dim3(256), 0, stream,
                           enc_b, wih_b, (const float*)nullptr, (float*)nullptr, gx_b, M_, 4 * H_, H_);
        hipLaunchKernelGGL(init_states, dim3(B_ * H_ / 256), dim3(256), 0, stream,
                           user_vec, game_vec, layer, hs0, cstate);
        for (int t = 0; t < T_; ++t) {
            const bool last = (t == T_ - 1);
            hipLaunchKernelGGL(lstm_step, dim3(64, 4), dim3(256), 0, stream,
                               (t & 1) ? hs1 : hs0, whh_b, gx_b, b_ih, b_hh, cstate,
                               (t & 1) ? hs0 : hs1,
                               last_layer ? nullptr : buf0, hb, t,
                               last ? (uv_out + layer * H_) : nullptr,
                               last ? (gv_out + layer * H_) : nullptr);
        }
    }

    // head: o1 = relu(lstm_out @ out1_w^T + out1_b), then 2-class log_softmax
    hipLaunchKernelGGL((gemm_mfma<64, 64, true, true, false>),
                       dim3((H_ / 2) / 64, M_ / 64), dim3(256), 0, stream,
                       hb, out1_wb, out1_b, o1, (u16*)nullptr, M_, H_ / 2, H_);
    hipLaunchKernelGGL(head_kernel, dim3(M_ / 4), dim3(256), 0, stream, o1, out2_w, out2_b, out);
}

// Round 10
// 710.233 us; speedup vs baseline: 1.2592x; 1.0267x over previous
//
#include <hip/hip_runtime.h>
#include <math.h>

// Problem constants
#define B_    256
#define T_    10
#define D_    512
#define H_    1024
#define FF_   2048
#define NHEAD 16
#define HD    64
#define M_    (B_ * T_)   // 2560 tokens
#define NL    2

typedef unsigned short u16;
typedef unsigned int   u32;
typedef __attribute__((ext_vector_type(8))) short bf16x8;
typedef __attribute__((ext_vector_type(4))) float f32x4;

__device__ inline float sigmoidf_(float x) { return 1.0f / (1.0f + expf(-x)); }
__device__ inline float b2f(u16 v) { return __uint_as_float(((u32)v) << 16); }
__device__ inline u16 f2b(float f) {
    u32 u = __float_as_uint(f);
    return (u16)((u + 0x7fffu + ((u >> 16) & 1u)) >> 16);
}

struct u16x8 { u16 v[8]; };
struct u16x4 { u16 v[4]; };

// ---------------------------------------------------------------------------
// Upfront convert kernel: 8 weight matrices + x -> bf16 arena, PLUS the
// LSTM initial states for both layers (h-init bf16, c-init f32). Both
// layers' initial states come from UNMODIFIED inputs (the reference updates
// uv/gv slice j only after layer j), so this is safe to hoist. Removes 2
// dispatches from the serial chain. 8 elems/thread, float4 loads.
// ---------------------------------------------------------------------------
__global__ __launch_bounds__(256) void cvt_weights(
    const float* __restrict__ fcw, const float* __restrict__ inp,
    const float* __restrict__ outp, const float* __restrict__ f1,
    const float* __restrict__ f2, const float* __restrict__ wih,
    const float* __restrict__ whh, const float* __restrict__ o1w,
    const float* __restrict__ xin,
    const float* __restrict__ uvec, const float* __restrict__ gvec,
    u16* __restrict__ wb, u16* __restrict__ hinit, float* __restrict__ cst)
{
    const int e = (blockIdx.x * 256 + threadIdx.x) * 8;
    if (e >= 19660800) {
        // c-init: cst[l][b*H+j] = gvec[b, l, j]   (f32 copy with remap)
        const int local = e - 19660800;
        const int l = local / 262144, rem = local - l * 262144;
        const int b = rem >> 10, j = rem & 1023;
        const float* src = gvec + (size_t)b * (NL * H_) + l * H_ + j;
        *(float4*)(cst + local)     = *(const float4*)src;
        *(float4*)(cst + local + 4) = *(const float4*)(src + 4);
        return;
    }
    if (e >= 19136512) {
        // h-init: hinit[l][b*H+j] = bf16(uvec[b, l, j])
        const int local = e - 19136512;
        const int l = local / 262144, rem = local - l * 262144;
        const int b = rem >> 10, j = rem & 1023;
        const float* src = uvec + (size_t)b * (NL * H_) + l * H_ + j;
        const float4 x0 = *(const float4*)src;
        const float4 x1 = *(const float4*)(src + 4);
        u16x8 r;
        r.v[0] = f2b(x0.x); r.v[1] = f2b(x0.y); r.v[2] = f2b(x0.z); r.v[3] = f2b(x0.w);
        r.v[4] = f2b(x1.x); r.v[5] = f2b(x1.y); r.v[6] = f2b(x1.z); r.v[7] = f2b(x1.w);
        *((u16x8*)(hinit + local)) = r;
        return;
    }
    const float* src; int off;
    if      (e <   524288) { src = fcw;  off = 0; }
    else if (e <  3670016) { src = inp;  off = 524288; }
    else if (e <  4718592) { src = outp; off = 3670016; }
    else if (e <  6815744) { src = f1;   off = 4718592; }
    else if (e <  8912896) { src = f2;   off = 6815744; }
    else if (e < 13107200) { src = wih;  off = 8912896; }
    else if (e < 17301504) { src = whh;  off = 13107200; }
    else if (e < 17825792) { src = o1w;  off = 17301504; }
    else                   { src = xin;  off = 17825792; }
    const float* p = src + (e - off);
    const float4 x0 = *((const float4*)p);
    const float4 x1 = *((const float4*)(p + 4));
    u16x8 r;
    r.v[0] = f2b(x0.x); r.v[1] = f2b(x0.y); r.v[2] = f2b(x0.z); r.v[3] = f2b(x0.w);
    r.v[4] = f2b(x1.x); r.v[5] = f2b(x1.y); r.v[6] = f2b(x1.z); r.v[7] = f2b(x1.w);
    *((u16x8*)(wb + e)) = r;
}

// ---------------------------------------------------------------------------
// MFMA bf16 GEMM — r6 proven config: BK=64 single-barrier double-buffer
// (64 KB LDS for 128x128, 2 blocks/CU). r7 (BK=32, 4 blk/CU) and r8
// (128x256, 264 unified regs -> 1 wave/SIMD cliff) both regressed; this is
// the bracketed local optimum. r9: bf16 epilogue repacks through the dead
// staging LDS -> coalesced u16x8 stores. 4 waves in 2x2; XCD-aware swizzle.
// ---------------------------------------------------------------------------
template<int BM, int BN, bool RELU, bool WF32, bool WB16>
__global__ __launch_bounds__(256) void gemm_mfma(const u16* __restrict__ A,
                                                 const u16* __restrict__ W,
                                                 const float* __restrict__ bias,
                                                 float* __restrict__ Cf,
                                                 u16* __restrict__ Cb,
                                                 int M, int N, int K)
{
    constexpr int MI  = BM / 32;
    constexpr int NJ  = BN / 32;
    constexpr int ASZ = 2 * BM * 32;   // u16 per A buffer (2 kk sub-tiles)
    constexpr int BSZ = 2 * BN * 32;
    constexpr int RPS = BN + 8;        // padded repack row stride (u16)
    __shared__ alignas(16) u16 smem[2 * ASZ + 2 * BSZ];
    u16* As = smem;
    u16* Bs = smem + 2 * ASZ;
    static_assert(BM * RPS <= 2 * ASZ + 2 * BSZ, "repack fits");

    int bx, by;
    {
        const int gx = gridDim.x, gy = gridDim.y;
        const int total = gx * gy;
        const int id = blockIdx.y * gx + blockIdx.x;
        if (((total & 7) == 0) && ((gy & 3) == 0)) {
            const int per = total >> 3;
            const int lid = (id & 7) * per + (id >> 3);  // XCD-contiguous
            const int band = gx << 2;
            const int g = lid / band;
            const int r = lid - g * band;
            by = (g << 2) + (r & 3);
            bx = r >> 2;
        } else { bx = blockIdx.x; by = blockIdx.y; }
    }

    const int wave = threadIdx.x >> 6;
    const int lane = threadIdx.x & 63;
    const int m0 = by * BM;
    const int n0 = bx * BN;
    const int wm = (wave >> 1) * (BM / 2);
    const int wn = (wave & 1) * (BN / 2);
    const int lr = lane >> 2;
    const int lc = (lane & 3) * 8;
    const int fr = lane & 15;
    const int kq = lane >> 4;

    auto stage = [&](int buf, int k0) {
#pragma unroll
        for (int cc = 0; cc < BM / 64; ++cc) {
            const int c = cc * 4 + wave;
            const u16* g = A + (size_t)(m0 + c * 16 + lr) * K + k0 + lc;
#pragma unroll
            for (int kk = 0; kk < 2; ++kk)
                __builtin_amdgcn_global_load_lds(
                    (const __attribute__((address_space(1))) void*)(g + kk * 32),
                    (__attribute__((address_space(3))) void*)(As + buf * ASZ + kk * BM * 32 + c * 512), 16, 0, 0);
        }
#pragma unroll
        for (int cc = 0; cc < BN / 64; ++cc) {
            const int c = cc * 4 + wave;
            const u16* g = W + (size_t)(n0 + c * 16 + lr) * K + k0 + lc;
#pragma unroll
            for (int kk = 0; kk < 2; ++kk)
                __builtin_amdgcn_global_load_lds(
                    (const __attribute__((address_space(1))) void*)(g + kk * 32),
                    (__attribute__((address_space(3))) void*)(Bs + buf * BSZ + kk * BN * 32 + c * 512), 16, 0, 0);
        }
    };

    f32x4 acc[MI][NJ] = {};

    stage(0, 0);
    __syncthreads();
    int cur = 0;
    for (int k0 = 0; k0 < K; k0 += 64) {
        if (k0 + 64 < K) stage(cur ^ 1, k0 + 64);
#pragma unroll
        for (int kk = 0; kk < 2; ++kk) {
            bf16x8 a[MI], b[NJ];
#pragma unroll
            for (int i = 0; i < MI; ++i)
                a[i] = *(const bf16x8*)(As + cur * ASZ + kk * BM * 32 + (wm + i * 16 + fr) * 32 + kq * 8);
#pragma unroll
            for (int j = 0; j < NJ; ++j)
                b[j] = *(const bf16x8*)(Bs + cur * BSZ + kk * BN * 32 + (wn + j * 16 + fr) * 32 + kq * 8);
#pragma unroll
            for (int i = 0; i < MI; ++i)
#pragma unroll
                for (int j = 0; j < NJ; ++j)
                    acc[i][j] = __builtin_amdgcn_mfma_f32_16x16x32_bf16(a[i], b[j], acc[i][j], 0, 0, 0);
        }
        __syncthreads();
        cur ^= 1;
    }

    // ---- epilogue ----
    u16* rp = smem;   // staging LDS is dead; repack view [BM][RPS]
#pragma unroll
    for (int i = 0; i < MI; ++i) {
#pragma unroll
        for (int j = 0; j < NJ; ++j) {
            const int cl = wn + j * 16 + fr;
            const float bv = bias ? bias[n0 + cl] : 0.0f;
#pragma unroll
            for (int r = 0; r < 4; ++r) {
                const int rl = wm + i * 16 + kq * 4 + r;
                float v = acc[i][j][r] + bv;
                if (RELU) v = fmaxf(v, 0.0f);
                if (WF32) Cf[(size_t)(m0 + rl) * N + n0 + cl] = v;
                if (WB16) rp[rl * RPS + cl] = f2b(v);
            }
        }
    }
    if (WB16) {
        __syncthreads();
        constexpr int CPR = BN / 8;               // 16B chunks per row
#pragma unroll
        for (int s = 0; s < BM * BN / 2048; ++s) {
            const int e   = s * 256 + threadIdx.x;
            const int row = e / CPR;
            const int ch  = e - row * CPR;
            *(u16x8*)(Cb + (size_t)(m0 + row) * N + n0 + ch * 8) =
                *(const u16x8*)(rp + row * RPS + ch * 8);
        }
    }
}

// ---------------------------------------------------------------------------
// Fused LSTM timestep (r6 proven config). Grid (64,4) = 256 blocks.
// Block = 64 b x 16 j (x4 gates = 64 W rows): 64x64 MFMA tile, BK=128
// double-buffered single-barrier K-loop (64 KB LDS), pointwise in-kernel.
// Gate biases (b_ih+b_hh) applied in the pointwise (gx GEMM is bias-free).
// Per-launch barrier between steps (coop grid.sync measured ~40 µs — r4).
// t=0 reads h from the precomputed hinit buffer (init_states folded away).
// ---------------------------------------------------------------------------
__global__ __launch_bounds__(256) void lstm_step(const u16* __restrict__ h_in,
                                                 const u16* __restrict__ Whh,
                                                 const u16* __restrict__ gx,
                                                 const float* __restrict__ bih,
                                                 const float* __restrict__ bhh,
                                                 float* __restrict__ cstate,
                                                 u16* __restrict__ h_out,
                                                 float* __restrict__ lout_f,
                                                 u16* __restrict__ lout_b,
                                                 int t,
                                                 float* __restrict__ hT_out,
                                                 float* __restrict__ cT_out)
{
    // [buf][As 8192 u16 | Bs 8192 u16] x2 = 64 KB; ghs (64x65 f32) aliases
    __shared__ alignas(16) u16 smem[2 * 16384];
    float* ghs = (float*)smem;

    const int j0 = blockIdx.x * 16;     // 0..1008
    const int b0 = blockIdx.y * 64;     // 0..192

    const int wave = threadIdx.x >> 6;
    const int lane = threadIdx.x & 63;
    const int wm = (wave >> 1) * 32;
    const int wn = (wave & 1) * 32;
    const int lr = lane >> 2;
    const int lc = (lane & 3) * 8;
    const int fr = lane & 15;
    const int kq = lane >> 4;

    auto stage = [&](int buf, int k0) {
        const u16* ga = h_in + (size_t)(b0 + wave * 16 + lr) * H_ + k0 + lc;
#pragma unroll
        for (int kk = 0; kk < 4; ++kk)
            __builtin_amdgcn_global_load_lds(
                (const __attribute__((address_space(1))) void*)(ga + kk * 32),
                (__attribute__((address_space(3))) void*)(smem + buf * 16384 + kk * 2048 + wave * 512), 16, 0, 0);
        const u16* gb = Whh + (size_t)(wave * H_ + j0 + lr) * H_ + k0 + lc;
#pragma unroll
        for (int kk = 0; kk < 4; ++kk)
            __builtin_amdgcn_global_load_lds(
                (const __attribute__((address_space(1))) void*)(gb + kk * 32),
                (__attribute__((address_space(3))) void*)(smem + buf * 16384 + 8192 + kk * 2048 + wave * 512), 16, 0, 0);
    };

    f32x4 acc[2][2] = {};

    stage(0, 0);
    __syncthreads();
    int cur = 0;
    for (int k0 = 0; k0 < H_; k0 += 128) {
        if (k0 + 128 < H_) stage(cur ^ 1, k0 + 128);
        const u16* As = smem + cur * 16384;
        const u16* Bs = As + 8192;
#pragma unroll
        for (int kk = 0; kk < 4; ++kk) {
            bf16x8 a[2], b[2];
#pragma unroll
            for (int i = 0; i < 2; ++i)
                a[i] = *(const bf16x8*)(As + kk * 2048 + (wm + i * 16 + fr) * 32 + kq * 8);
#pragma unroll
            for (int j = 0; j < 2; ++j)
                b[j] = *(const bf16x8*)(Bs + kk * 2048 + (wn + j * 16 + fr) * 32 + kq * 8);
#pragma unroll
            for (int i = 0; i < 2; ++i)
#pragma unroll
                for (int j = 0; j < 2; ++j)
                    acc[i][j] = __builtin_amdgcn_mfma_f32_16x16x32_bf16(a[i], b[j], acc[i][j], 0, 0, 0);
        }
        __syncthreads();
        cur ^= 1;
    }

    // dump ghh tile -> ghs[b-local][rl] (stride 65; smem is dead now)
#pragma unroll
    for (int i = 0; i < 2; ++i)
#pragma unroll
        for (int j = 0; j < 2; ++j) {
            const int rl = wn + j * 16 + fr;
#pragma unroll
            for (int r = 0; r < 4; ++r) {
                const int bl = wm + i * 16 + kq * 4 + r;
                ghs[bl * 65 + rl] = acc[i][j][r];
            }
        }
    __syncthreads();

    // pointwise: thread -> (b_, 4 consecutive j); gates at rl = g*16 + jj
    {
        const int bl = threadIdx.x >> 2;             // 0..63
        const int jq = threadIdx.x & 3;              // 0..3
        const int b_ = b0 + bl;
        const int jbase = jq * 4;                    // jj = jbase+q in 0..15
        const u16* g1 = gx + (size_t)(b_ * T_ + t) * (4 * H_) + j0 + jbase;
        float hh4[4], c4[4];
#pragma unroll
        for (int q = 0; q < 4; ++q) {
            const int jj = jbase + q;
            const int jg = j0 + jbase + q;
            const float gi = b2f(g1[q])          + bih[jg]           + bhh[jg]           + ghs[bl * 65 +  0 + jj];
            const float gf = b2f(g1[H_ + q])     + bih[H_ + jg]      + bhh[H_ + jg]      + ghs[bl * 65 + 16 + jj];
            const float gg = b2f(g1[2 * H_ + q]) + bih[2 * H_ + jg]  + bhh[2 * H_ + jg]  + ghs[bl * 65 + 32 + jj];
            const float go = b2f(g1[3 * H_ + q]) + bih[3 * H_ + jg]  + bhh[3 * H_ + jg]  + ghs[bl * 65 + 48 + jj];
            const int sid = b_ * H_ + jg;
            const float c  = sigmoidf_(gf) * cstate[sid] + sigmoidf_(gi) * tanhf(gg);
            const float hh = sigmoidf_(go) * tanhf(c);
            cstate[sid] = c;
            c4[q] = c;
            hh4[q] = hh;
        }
        u16*   hp = h_out  + (size_t)b_ * H_ + j0 + jbase;
        u16*   lb = lout_b + (size_t)(b_ * T_ + t) * H_ + j0 + jbase;
#pragma unroll
        for (int q = 0; q < 4; ++q) {
            const u16 hb16 = f2b(hh4[q]);
            hp[q] = hb16;
            lb[q] = hb16;
        }
        if (lout_f) {
            float* lf = lout_f + (size_t)(b_ * T_ + t) * H_ + j0 + jbase;
#pragma unroll
            for (int q = 0; q < 4; ++q) lf[q] = hh4[q];
        }
        if (hT_out) {
#pragma unroll
            for (int q = 0; q < 4; ++q) {
                hT_out[(size_t)b_ * (NL * H_) + j0 + jbase + q] = hh4[q];
                cT_out[(size_t)b_ * (NL * H_) + j0 + jbase + q] = c4[q];
            }
        }
    }
}

// ---------------------------------------------------------------------------
// Causal MHA for one (batch, head), bf16 qkv in, bf16 ctx out.
// r10: u16x4 vectorized loads/stores (were scalar u16).
// ---------------------------------------------------------------------------
__global__ __launch_bounds__(256) void attn_kernel(const u16* __restrict__ qkv,
                                                   u16* __restrict__ ctx)
{
    const int bh = blockIdx.x;
    const int b  = bh >> 4;
    const int h  = bh & 15;

    __shared__ float q[T_][HD], k[T_][HD], v[T_][HD];
    __shared__ float p[T_][T_];

    for (int idx4 = threadIdx.x * 4; idx4 < T_ * HD; idx4 += 1024) {
        const int t = idx4 >> 6, d = idx4 & 63;
        const u16* row = qkv + (size_t)(b * T_ + t) * (3 * H_) + h * HD + d;
        const u16x4 qv = *(const u16x4*)(row);
        const u16x4 kv = *(const u16x4*)(row + H_);
        const u16x4 vv = *(const u16x4*)(row + 2 * H_);
#pragma unroll
        for (int i = 0; i < 4; ++i) {
            q[t][d + i] = b2f(qv.v[i]);
            k[t][d + i] = b2f(kv.v[i]);
            v[t][d + i] = b2f(vv.v[i]);
        }
    }
    __syncthreads();

    if (threadIdx.x < T_ * T_) {
        const int qi = threadIdx.x / T_, ki = threadIdx.x % T_;
        float s = 0.0f;
        if (ki <= qi) {
            for (int d = 0; d < HD; ++d) s = fmaf(q[qi][d], k[ki][d], s);
            s *= 0.125f;
        }
        p[qi][ki] = s;
    }
    __syncthreads();

    if (threadIdx.x < T_) {
        const int rq = threadIdx.x;
        float mx = -1e30f;
        for (int ki = 0; ki <= rq; ++ki) mx = fmaxf(mx, p[rq][ki]);
        float sum = 0.0f;
        for (int ki = 0; ki <= rq; ++ki) { const float e = expf(p[rq][ki] - mx); p[rq][ki] = e; sum += e; }
        const float inv = 1.0f / sum;
        for (int ki = 0; ki <= rq; ++ki) p[rq][ki] *= inv;
        for (int ki = rq + 1; ki < T_; ++ki) p[rq][ki] = 0.0f;
    }
    __syncthreads();

    for (int idx4 = threadIdx.x * 4; idx4 < T_ * HD; idx4 += 1024) {
        const int t = idx4 >> 6, d = idx4 & 63;
        float s[4] = {0.0f, 0.0f, 0.0f, 0.0f};
        for (int ki = 0; ki <= t; ++ki) {
            const float pv = p[t][ki];
#pragma unroll
            for (int i = 0; i < 4; ++i) s[i] = fmaf(pv, v[ki][d + i], s[i]);
        }
        u16x4 o = { { f2b(s[0]), f2b(s[1]), f2b(s[2]), f2b(s[3]) } };
        *(u16x4*)(ctx + (size_t)(b * T_ + t) * H_ + h * HD + d) = o;
    }
}

// ---------------------------------------------------------------------------
// Fused residual-add + LayerNorm, float4 I/O. Writes f32 and/or bf16.
// ---------------------------------------------------------------------------
__global__ __launch_bounds__(256) void ln_kernel(const float* __restrict__ x,
                                                 const float* __restrict__ res,
                                                 const float* __restrict__ w,
                                                 const float* __restrict__ b,
                                                 float* __restrict__ outf,
                                                 u16* __restrict__ outb)
{
    const int row = blockIdx.x;
    const int c = threadIdx.x * 4;
    const float4 xv = *(const float4*)(x + (size_t)row * H_ + c);
    const float4 rv = *(const float4*)(res + (size_t)row * H_ + c);
    float vals[4] = { xv.x + rv.x, xv.y + rv.y, xv.z + rv.z, xv.w + rv.w };
    float s = 0.0f, s2 = 0.0f;
#pragma unroll
    for (int i = 0; i < 4; ++i) { s += vals[i]; s2 = fmaf(vals[i], vals[i], s2); }
    for (int off = 32; off; off >>= 1) {
        s  += __shfl_down(s, off);
        s2 += __shfl_down(s2, off);
    }
    __shared__ float rs_[4], rs2_[4];
    const int wave = threadIdx.x >> 6, lane = threadIdx.x & 63;
    if (lane == 0) { rs_[wave] = s; rs2_[wave] = s2; }
    __syncthreads();
    const float st  = rs_[0] + rs_[1] + rs_[2] + rs_[3];
    const float st2 = rs2_[0] + rs2_[1] + rs2_[2] + rs2_[3];
    const float m   = st * (1.0f / 1024.0f);
    const float var = st2 * (1.0f / 1024.0f) - m * m;
    const float rsv = rsqrtf(var + 1e-5f);
    const float4 wv = *(const float4*)(w + c);
    const float4 bv = *(const float4*)(b + c);
    float o[4];
    o[0] = (vals[0] - m) * rsv * wv.x + bv.x;
    o[1] = (vals[1] - m) * rsv * wv.y + bv.y;
    o[2] = (vals[2] - m) * rsv * wv.z + bv.z;
    o[3] = (vals[3] - m) * rsv * wv.w + bv.w;
    if (outf) *(float4*)(outf + (size_t)row * H_ + c) = make_float4(o[0], o[1], o[2], o[3]);
    if (outb) {
        u16x4 ob = { { f2b(o[0]), f2b(o[1]), f2b(o[2]), f2b(o[3]) } };
        *(u16x4*)(outb + (size_t)row * H_ + c) = ob;
    }
}

// ---------------------------------------------------------------------------
// Head: o = o1 @ out2_w^T + out2_b (N=2) + log_softmax. One wave per token.
// ---------------------------------------------------------------------------
__global__ __launch_bounds__(256) void head_kernel(const float* __restrict__ o1,
                                                   const float* __restrict__ w2,
                                                   const float* __restrict__ b2,
                                                   float* __restrict__ out)
{
    const int token = blockIdx.x * 4 + (threadIdx.x >> 6);
    const int lane  = threadIdx.x & 63;
    const float* row = o1 + (size_t)token * (H_ / 2);
    float s0 = 0.0f, s1 = 0.0f;
    for (int c = lane; c < H_ / 2; c += 64) {
        const float xv = row[c];
        s0 = fmaf(xv, w2[c], s0);
        s1 = fmaf(xv, w2[H_ / 2 + c], s1);
    }
    for (int off = 32; off; off >>= 1) {
        s0 += __shfl_down(s0, off);
        s1 += __shfl_down(s1, off);
    }
    if (lane == 0) {
        const float o0 = s0 + b2[0];
        const float o1v = s1 + b2[1];
        const float mx = fmaxf(o0, o1v);
        const float lse = mx + logf(expf(o0 - mx) + expf(o1v - mx));
        out[(size_t)token * 2 + 0] = o0 - lse;
        out[(size_t)token * 2 + 1] = o1v - lse;
    }
}

// ---------------------------------------------------------------------------
extern "C" void kernel_launch(void* const* d_in, const int* in_sizes, int n_in,
                              void* d_out, int out_size, void* d_ws, size_t ws_size,
                              hipStream_t stream)
{
    const float* x         = (const float*)d_in[0];
    const float* user_vec  = (const float*)d_in[1];
    const float* game_vec  = (const float*)d_in[2];
    const float* fc_w      = (const float*)d_in[3];
    const float* fc_b      = (const float*)d_in[4];
    const float* in_proj_w = (const float*)d_in[5];
    const float* in_proj_b = (const float*)d_in[6];
    const float* out_proj_w= (const float*)d_in[7];
    const float* out_proj_b= (const float*)d_in[8];
    const float* ln1_w     = (const float*)d_in[9];
    const float* ln1_b     = (const float*)d_in[10];
    const float* ff1_w     = (const float*)d_in[11];
    const float* ff1_b     = (const float*)d_in[12];
    const float* ff2_w     = (const float*)d_in[13];
    const float* ff2_b     = (const float*)d_in[14];
    const float* ln2_w     = (const float*)d_in[15];
    const float* ln2_b     = (const float*)d_in[16];
    const float* w_ih      = (const float*)d_in[17];
    const float* w_hh      = (const float*)d_in[18];
    const float* b_ih      = (const float*)d_in[19];
    const float* b_hh      = (const float*)d_in[20];
    const float* out1_w    = (const float*)d_in[21];
    const float* out1_b    = (const float*)d_in[22];
    const float* out2_w    = (const float*)d_in[23];
    const float* out2_b    = (const float*)d_in[24];
    float* out = (float*)d_out;

    // ---- byte arena ----
    char* base = (char*)d_ws;
    u16* wb = (u16*)base;               // bf16 arena: 8 weights + x (contiguous)
    u16* fc_wb   = wb;
    u16* inp_wb  = wb + 524288;
    u16* outp_wb = wb + 3670016;
    u16* ff1_wb  = wb + 4718592;
    u16* ff2_wb  = wb + 6815744;
    u16* wih_b   = wb + 8912896;
    u16* whh_b   = wb + 13107200;
    u16* out1_wb = wb + 17301504;
    u16* x_b     = wb + 17825792;       // [M,D] bf16
    char* A1 = base + 38273024;   // 21.0 MB: qkv_b | tmp1+tmp2 f32 | gx_b | o1
    char* S1 = A1 + 20971520;     // 10.5 MB: ff1_b
    char* S2 = S1 + 10485760;     //  5.2 MB: ctx_b | ln1_b | enc_b
    u16*  hb = (u16*)(S2 + 5242880);              // h bf16 [M,H]
    float* buf0 = (float*)((char*)hb + 5242880);  // h f32 [M,H]
    u16*  hs0 = (u16*)((char*)buf0 + 10485760);   // LSTM h ping
    u16*  hs1 = (u16*)((char*)hs0 + 524288);      // LSTM h pong
    u16*  hinit = (u16*)((char*)hs1 + 524288);    // [2][B*H] bf16 init h
    float* cst  = (float*)((char*)hinit + 1048576); // [2][B*H] f32 c states

    u16*   qkv_b = (u16*)A1;
    float* tmp1  = (float*)A1;
    float* tmp2  = (float*)(A1 + 10485760);
    u16*   gx_b  = (u16*)A1;
    float* o1    = (float*)A1;
    u16*   ff1b  = (u16*)S1;
    u16*   ctx_b = (u16*)S2;
    u16*   ln1b  = (u16*)S2;
    u16*   enc_b = (u16*)S2;

    float* gv_out = out + (size_t)M_ * 2;            // cT [B,NL,H]
    float* uv_out = gv_out + (size_t)B_ * NL * H_;   // hT [B,NL,H]

    // 19136512 weights+x, +524288 hinit, +524288 cst = 20185088 elems
    hipLaunchKernelGGL(cvt_weights, dim3(20185088 / 8 / 256), dim3(256), 0, stream,
                       fc_w, in_proj_w, out_proj_w, ff1_w, ff2_w, w_ih, w_hh, out1_w,
                       x, user_vec, game_vec, wb, hinit, cst);

    // fc: h = relu(x @ fc_w^T + fc_b) -> f32 + bf16
    hipLaunchKernelGGL((gemm_mfma<64, 128, true, true, true>),
                       dim3(H_ / 128, M_ / 64), dim3(256), 0, stream,
                       x_b, fc_wb, fc_b, buf0, hb, M_, H_, D_);

    for (int layer = 0; layer < NL; ++layer) {
        const bool last_layer = (layer == NL - 1);
        // qkv (bf16 only)
        hipLaunchKernelGGL((gemm_mfma<128, 128, false, false, true>),
                           dim3(3 * H_ / 128, M_ / 128), dim3(256), 0, stream,
                           hb, inp_wb, in_proj_b, (float*)nullptr, qkv_b, M_, 3 * H_, H_);
        hipLaunchKernelGGL(attn_kernel, dim3(B_ * NHEAD), dim3(256), 0, stream, qkv_b, ctx_b);
        // attn out-proj (f32 only)
        hipLaunchKernelGGL((gemm_mfma<64, 128, false, true, false>),
                           dim3(H_ / 128, M_ / 64), dim3(256), 0, stream,
                           ctx_b, outp_wb, out_proj_b, tmp1, (u16*)nullptr, M_, H_, H_);
        hipLaunchKernelGGL(ln_kernel, dim3(M_), dim3(256), 0, stream,
                           buf0, tmp1, ln1_w, ln1_b, tmp2, ln1b);
        // ff1 relu (bf16 only)
        hipLaunchKernelGGL((gemm_mfma<128, 128, true, false, true>),
                           dim3(FF_ / 128, M_ / 128), dim3(256), 0, stream,
                           ln1b, ff1_wb, ff1_b, (float*)nullptr, ff1b, M_, FF_, H_);
        // ff2 (f32 only)
        hipLaunchKernelGGL((gemm_mfma<64, 128, false, true, false>),
                           dim3(H_ / 128, M_ / 64), dim3(256), 0, stream,
                           ff1b, ff2_wb, ff2_b, tmp1, (u16*)nullptr, M_, H_, FF_);
        hipLaunchKernelGGL(ln_kernel, dim3(M_), dim3(256), 0, stream,
                           tmp2, tmp1, ln2_w, ln2_b, (float*)nullptr, enc_b);
        // LSTM input gates for all t (bf16 only; biases applied in lstm_step)
        hipLaunchKernelGGL((gemm_mfma<128, 128, false, false, true>),
                           dim3(4 * H_ / 128, M_ / 128), dim3(256), 0, stream,
                           enc_b, wih_b, (const float*)nullptr, (float*)nullptr, gx_b, M_, 4 * H_, H_);
        float* cstate = cst + (size_t)layer * (B_ * H_);
        const u16* hinit_l = hinit + (size_t)layer * (B_ * H_);
        for (int t = 0; t < T_; ++t) {
            const bool last = (t == T_ - 1);
            const u16* hin = (t == 0) ? hinit_l : ((t & 1) ? hs1 : hs0);
            u16* hout = (t & 1) ? hs0 : hs1;
            hipLaunchKernelGGL(lstm_step, dim3(64, 4), dim3(256), 0, stream,
                               hin, whh_b, gx_b, b_ih, b_hh, cstate, hout,
                               last_layer ? nullptr : buf0, hb, t,
                               last ? (uv_out + layer * H_) : nullptr,
                               last ? (gv_out + layer * H_) : nullptr);
        }
    }

    // head: o1 = relu(lstm_out @ out1_w^T + out1_b), then 2-class log_softmax
    hipLaunchKernelGGL((gemm_mfma<64, 64, true, true, false>),
                       dim3((H_ / 2) / 64, M_ / 64), dim3(256), 0, stream,
                       hb, out1_wb, out1_b, o1, (u16*)nullptr, M_, H_ / 2, H_);
    hipLaunchKernelGGL(head_kernel, dim3(M_ / 4), dim3(256), 0, stream, o1, out2_w, out2_b, out);
}